// Round 1
// baseline (425.480 us; speedup 1.0000x reference)
//
#include <hip/hip_runtime.h>

#define WIN_N 64
#define CDIM  256

typedef __attribute__((ext_vector_type(8))) short bf16x8;
typedef __attribute__((ext_vector_type(4))) float f32x4;
typedef unsigned short u16;
typedef unsigned int   u32;

__device__ __forceinline__ u16 f2bf(float f) {
  u32 u = __builtin_bit_cast(u32, f);
  u = (u + 0x7FFFu + ((u >> 16) & 1u)) >> 16;
  return (u16)u;
}

// ws layout (bytes):
//      0 : Wq bf16 [256][256]
// 131072 : Wk bf16 [256][256]
// 262144 : Wv bf16 [256][256]
// 393216 : rpbT f32 [8][64][64]    rpbT[h][k][i] = bias_table[rel_index[i][k]][h]
// 524288 : maskT f32 [64][64][64]  maskT[w][k][i] = mask[w][i][k]
// total 1572864 B

__global__ void prep_kernel(const float* __restrict__ Wq, const float* __restrict__ Wk,
                            const float* __restrict__ Wv, const float* __restrict__ btab,
                            const int* __restrict__ ridx, const float* __restrict__ amask,
                            u16* __restrict__ wb, float* __restrict__ rpbT,
                            float* __restrict__ maskT) {
  int bid = blockIdx.x;
  int tid = threadIdx.x;
  if (bid < 768) {
    int gid = bid * 256 + tid;                 // 0..196607 over 3 weight matrices
    int m = gid >> 16, e = gid & 65535;
    const float* W = (m == 0) ? Wq : (m == 1) ? Wk : Wv;
    wb[gid] = f2bf(W[e]);
  } else if (bid < 896) {
    int e = (bid - 768) * 256 + tid;           // 0..32767  [h][k][i]
    int h = e >> 12, k = (e >> 6) & 63, i = e & 63;
    rpbT[e] = btab[ridx[i * 64 + k] * 8 + h];
  } else {
    int e = (bid - 896) * 256 + tid;           // 0..262143 [win][k][i]
    int wv = e >> 12, k = (e >> 6) & 63, i = e & 63;
    maskT[e] = amask[(wv * 64 + i) * 64 + k];
  }
}

// One block per window. 4 waves; wave w owns output channels [64w, 64w+64) = heads 2w, 2w+1.
// LDS 128 KiB:
//   [0,32K)      Xs  [64][256] bf16 (swizzled), later reused as Pbuf (wave w at w*8K: [64 q][64 k])
//   [32K,64K)    Qs  per-wave [64 tok][64 d] bf16 (swizzled), Q pre-scaled by 1/sqrt(32)
//   [64K,96K)    Ks  per-wave [64 tok][64 d]
//   [96K,128K)   VTs per-wave [64 d][64 tok]
__global__ __launch_bounds__(256, 1) void swin_attn_kernel(
    const float* __restrict__ X, const u16* __restrict__ Wb,
    const float* __restrict__ bq, const float* __restrict__ bk,
    const float* __restrict__ bv, const float* __restrict__ rpbT,
    const float* __restrict__ maskT, float* __restrict__ out) {
  __shared__ int4 smem4[8192];  // 128 KiB
  char* smem = (char*)smem4;

  const int tid = threadIdx.x;
  const int l  = tid & 63;
  const int w  = tid >> 6;
  const int lr = l & 15;
  const int lg = l >> 4;
  const int b  = blockIdx.x;
  const int win = b & 63;

  const float* Xb = X + (size_t)b * (WIN_N * CDIM);

  // ---- stage X -> bf16 LDS (swizzled rows of 512B) ----
#pragma unroll
  for (int it = 0; it < 8; ++it) {
    int c = tid + it * 256;          // 2048 chunks of 8 elems
    int r = c >> 5;
    int k0 = (c & 31) << 3;
    const float* xp = Xb + r * 256 + k0;
    float4 f0 = *(const float4*)xp;
    float4 f1 = *(const float4*)(xp + 4);
    int p0 = (int)((u32)f2bf(f0.x) | ((u32)f2bf(f0.y) << 16));
    int p1 = (int)((u32)f2bf(f0.z) | ((u32)f2bf(f0.w) << 16));
    int p2 = (int)((u32)f2bf(f1.x) | ((u32)f2bf(f1.y) << 16));
    int p3 = (int)((u32)f2bf(f1.z) | ((u32)f2bf(f1.w) << 16));
    int off = (r * 512 + k0 * 2) ^ ((r & 7) << 4);
    *(int4*)(smem + off) = make_int4(p0, p1, p2, p3);
  }
  __syncthreads();

  const int QS = 32768 + w * 8192;
  const int KS = 65536 + w * 8192;
  const int VT = 98304 + w * 8192;
  const int PB = w * 8192;

  const float SCALE = 0.17677669529663687f;  // 1/sqrt(32)

  // ---- QKV projection: per wave 64x64 output tile per matrix ----
#pragma unroll
  for (int m = 0; m < 3; ++m) {
    const u16* Wm = Wb + m * 65536;
    const float* bp = (m == 0) ? bq : (m == 1) ? bk : bv;
    float bias_v[4];
#pragma unroll
    for (int jf = 0; jf < 4; ++jf) bias_v[jf] = bp[w * 64 + jf * 16 + lr];

    f32x4 acc[4][4];
#pragma unroll
    for (int rf = 0; rf < 4; ++rf)
#pragma unroll
      for (int jf = 0; jf < 4; ++jf) acc[rf][jf] = (f32x4)(0.f);

#pragma unroll
    for (int ks = 0; ks < 8; ++ks) {
      int kb = ks * 32 + lg * 8;
      bf16x8 a[4];
#pragma unroll
      for (int rf = 0; rf < 4; ++rf) {
        int row = lr + rf * 16;
        a[rf] = *(const bf16x8*)(smem + ((row * 512 + kb * 2) ^ ((row & 7) << 4)));
      }
#pragma unroll
      for (int jf = 0; jf < 4; ++jf) {
        bf16x8 bfr = *(const bf16x8*)(Wm + (w * 64 + jf * 16 + lr) * 256 + kb);
#pragma unroll
        for (int rf = 0; rf < 4; ++rf)
          acc[rf][jf] = __builtin_amdgcn_mfma_f32_16x16x32_bf16(a[rf], bfr, acc[rf][jf], 0, 0, 0);
      }
    }
    if (m < 2) {
      // Q/K -> [token][d] bf16, swizzled; Q folded with softmax scale
      int base = (m == 0) ? QS : KS;
      float s = (m == 0) ? SCALE : 1.0f;
#pragma unroll
      for (int rf = 0; rf < 4; ++rf)
#pragma unroll
        for (int jf = 0; jf < 4; ++jf) {
          int dloc = jf * 16 + lr;
#pragma unroll
          for (int reg = 0; reg < 4; ++reg) {
            int i = lg * 4 + reg + rf * 16;
            u16 v = f2bf((acc[rf][jf][reg] + bias_v[jf]) * s);
            *(u16*)(smem + base + ((i * 128 + dloc * 2) ^ ((i & 7) << 4))) = v;
          }
        }
    } else {
      // V -> VT[d][token], 8B packed writes (4 consecutive tokens per C-reg group)
#pragma unroll
      for (int rf = 0; rf < 4; ++rf)
#pragma unroll
        for (int jf = 0; jf < 4; ++jf) {
          int dloc = jf * 16 + lr;
          int i0 = lg * 4 + rf * 16;
          u32 lo = (u32)f2bf(acc[rf][jf][0] + bias_v[jf]) |
                   ((u32)f2bf(acc[rf][jf][1] + bias_v[jf]) << 16);
          u32 hi = (u32)f2bf(acc[rf][jf][2] + bias_v[jf]) |
                   ((u32)f2bf(acc[rf][jf][3] + bias_v[jf]) << 16);
          int off = VT + ((dloc * 128 + i0 * 2) ^ ((dloc & 7) << 4));
          *(uint2*)(smem + off) = make_uint2(lo, hi);
        }
    }
  }
  __syncthreads();  // all waves done reading Xs; PB may now overwrite it

  // ---- attention, 2 heads per wave ----
#pragma unroll
  for (int hl = 0; hl < 2; ++hl) {
    const int d0 = hl * 32;
    const int h = w * 2 + hl;
    const int kb = (d0 + lg * 8) * 2;

    bf16x8 aK[4], bQv[4];
#pragma unroll
    for (int rf = 0; rf < 4; ++rf) {
      int row = lr + rf * 16;
      aK[rf]  = *(const bf16x8*)(smem + KS + ((row * 128 + kb) ^ ((row & 7) << 4)));
      bQv[rf] = *(const bf16x8*)(smem + QS + ((row * 128 + kb) ^ ((row & 7) << 4)));
    }
    f32x4 zero = (f32x4)(0.f);
    float p[4][4][4];  // [rf(k-blocks)][cf(i-blocks)][reg]
    const float* rp = rpbT + h * 4096;
    const float* mp = maskT + win * 4096;
#pragma unroll
    for (int rf = 0; rf < 4; ++rf)
#pragma unroll
      for (int cf = 0; cf < 4; ++cf) {
        f32x4 st = __builtin_amdgcn_mfma_f32_16x16x32_bf16(aK[rf], bQv[cf], zero, 0, 0, 0);
#pragma unroll
        for (int reg = 0; reg < 4; ++reg) {
          int k = lg * 4 + reg + rf * 16;
          int i = lr + cf * 16;
          p[rf][cf][reg] = st[reg] + rp[k * 64 + i] + mp[k * 64 + i];
        }
      }
    // softmax over k (rows): in-lane over rf/reg, then xor-16/32 across row groups
#pragma unroll
    for (int cf = 0; cf < 4; ++cf) {
      float mx = p[0][cf][0];
#pragma unroll
      for (int rf = 0; rf < 4; ++rf)
#pragma unroll
        for (int reg = 0; reg < 4; ++reg) mx = fmaxf(mx, p[rf][cf][reg]);
      mx = fmaxf(mx, __shfl_xor(mx, 16));
      mx = fmaxf(mx, __shfl_xor(mx, 32));
      float sum = 0.f;
#pragma unroll
      for (int rf = 0; rf < 4; ++rf)
#pragma unroll
        for (int reg = 0; reg < 4; ++reg) {
          float e = exp2f((p[rf][cf][reg] - mx) * 1.4426950408889634f);
          p[rf][cf][reg] = e;
          sum += e;
        }
      sum += __shfl_xor(sum, 16);
      sum += __shfl_xor(sum, 32);
      float rs = 1.0f / sum;
#pragma unroll
      for (int rf = 0; rf < 4; ++rf)
#pragma unroll
        for (int reg = 0; reg < 4; ++reg) p[rf][cf][reg] *= rs;
    }
    // P -> Pbuf[i][k] bf16, 8B packed (4 consecutive k per reg group)
#pragma unroll
    for (int rf = 0; rf < 4; ++rf)
#pragma unroll
      for (int cf = 0; cf < 4; ++cf) {
        int i = lr + cf * 16;
        int k0 = lg * 4 + rf * 16;
        u32 lo = (u32)f2bf(p[rf][cf][0]) | ((u32)f2bf(p[rf][cf][1]) << 16);
        u32 hi = (u32)f2bf(p[rf][cf][2]) | ((u32)f2bf(p[rf][cf][3]) << 16);
        *(uint2*)(smem + PB + ((i * 128 + k0 * 2) ^ ((i & 7) << 4))) = make_uint2(lo, hi);
      }
    // PV: ctx[64 q][32 d]
    f32x4 o[4][2];
#pragma unroll
    for (int rf = 0; rf < 4; ++rf) { o[rf][0] = zero; o[rf][1] = zero; }
#pragma unroll
    for (int ks2 = 0; ks2 < 2; ++ks2) {
      int kb2 = (ks2 * 32 + lg * 8) * 2;
      bf16x8 aP[4];
#pragma unroll
      for (int rf = 0; rf < 4; ++rf) {
        int row = lr + rf * 16;
        aP[rf] = *(const bf16x8*)(smem + PB + ((row * 128 + kb2) ^ ((row & 7) << 4)));
      }
#pragma unroll
      for (int jf = 0; jf < 2; ++jf) {
        int vrow = d0 + jf * 16 + lr;
        bf16x8 bV = *(const bf16x8*)(smem + VT + ((vrow * 128 + kb2) ^ ((vrow & 7) << 4)));
#pragma unroll
        for (int rf = 0; rf < 4; ++rf)
          o[rf][jf] = __builtin_amdgcn_mfma_f32_16x16x32_bf16(aP[rf], bV, o[rf][jf], 0, 0, 0);
      }
    }
    float* ob = out + (size_t)b * (WIN_N * CDIM);
#pragma unroll
    for (int rf = 0; rf < 4; ++rf)
#pragma unroll
      for (int jf = 0; jf < 2; ++jf)
#pragma unroll
        for (int reg = 0; reg < 4; ++reg) {
          int i = lg * 4 + reg + rf * 16;
          int cc = w * 64 + d0 + jf * 16 + lr;
          ob[i * 256 + cc] = o[rf][jf][reg];
        }
  }
}

extern "C" void kernel_launch(void* const* d_in, const int* in_sizes, int n_in,
                              void* d_out, int out_size, void* d_ws, size_t ws_size,
                              hipStream_t stream) {
  const float* X  = (const float*)d_in[0];
  const float* am = (const float*)d_in[1];
  const float* Wq = (const float*)d_in[2];
  const float* bq = (const float*)d_in[3];
  const float* Wk = (const float*)d_in[4];
  const float* bk = (const float*)d_in[5];
  const float* Wv = (const float*)d_in[6];
  const float* bv = (const float*)d_in[7];
  const float* bt = (const float*)d_in[8];
  const int*   ri = (const int*)d_in[9];

  u16*   wb    = (u16*)d_ws;
  float* rpbT  = (float*)((char*)d_ws + 393216);
  float* maskT = (float*)((char*)d_ws + 524288);

  prep_kernel<<<1920, 256, 0, stream>>>(Wq, Wk, Wv, bt, ri, am, wb, rpbT, maskT);
  swin_attn_kernel<<<2048, 256, 0, stream>>>(X, wb, bq, bk, bv, rpbT, maskT, (float*)d_out);
}